// Round 3
// baseline (1288.734 us; speedup 1.0000x reference)
//
#include <hip/hip_runtime.h>
#include <cstddef>

#define BB   16384
#define TT_  100
#define FF   64
#define K4   20
#define HH   5
#define NOUT 3

__device__ __forceinline__ float tanhf_fast(float x) {
    // tanh(x) = 1 - 2/(e^{2x}+1); safe at +/-inf
    return 1.0f - 2.0f * __builtin_amdgcn_rcpf(__expf(2.0f * x) + 1.0f);
}
// DPP quad-perm (VALU cross-lane within groups of 4, no LDS pipe).
// 0xB1 = xor1 [1,0,3,2]; 0x4E = xor2 [2,3,0,1]; 0x00 = broadcast quad-lane 0.
template <int CTRL>
__device__ __forceinline__ float qp(float v) {
    return __int_as_float(__builtin_amdgcn_update_dpp(
        0, __float_as_int(v), CTRL, 0xF, 0xF, true));
}

// ===========================================================================
// K1: projection.  z[t][k][b] = x[b,t,:] @ W1[:,k] + b1[k]   (layout [T][20][B])
// Wave = 16 batches x 4 timesteps, quad per batch (lane s owns f = i*16+4s+cc).
// 80 LDS W-reads per wave now feed 1280 FMAs (4 t amortization, round-2 was
// 80 reads / 320 FMA -> LDS-bound).  Quad reduce via DPP adds (VALU, no LDS).
// W tile XOR-swizzled: slot' = k4 ^ ((f>>2)&3), k4=4 replicated in slots 4-7,
// so the 4 s-groups of a read instr hit disjoint 16B slots -> conflict-free.
// Loads: 64B contiguous per quad per instr; stores: 64B chunks per k-row.
// HBM-bound target: (419+131) MB -> ~110-140 us.
// ===========================================================================
__global__ __launch_bounds__(256, 2) void proj_kernel(
    const float* __restrict__ x, const float* __restrict__ W1,
    const float* __restrict__ b1, float* __restrict__ z)
{
    __shared__ float sW[FF * 32];          // rows of 8 16B slots (swizzled)
    const int tid  = threadIdx.x;
    const int wv   = tid >> 6;
    const int lane = tid & 63;
    const int q    = lane >> 2;            // batch within 16-group
    const int s    = lane & 3;             // quad sub-lane (f sub-block)
    const int b    = (blockIdx.x << 6) + (wv << 4) + q;
    const int t0   = blockIdx.y << 2;

    // stage W1 swizzled: one-time
    for (int i = tid; i < FF * K4; i += 256) {
        const int f  = i / K4;
        const int k  = i - f * K4;
        const int k4 = k >> 2, c = k & 3;
        const int sx = (f >> 2) & 3;
        const float v = W1[i];
        float* row = &sW[f * 32];
        if (k4 < 4) {
            row[((k4 ^ sx) << 2) + c] = v;
        } else {                            // replicate k=16..19 into slots 4-7
            row[16 + c] = v; row[20 + c] = v; row[24 + c] = v; row[28 + c] = v;
        }
    }

    // x loads: per t, quad covers 64B contiguous per instruction
    float4 xv[4][4];
#pragma unroll
    for (int t = 0; t < 4; ++t) {
        const float4* rowp = (const float4*)(x + ((size_t)b * TT_ + t0 + t) * FF);
#pragma unroll
        for (int i = 0; i < 4; ++i) xv[t][i] = rowp[i * 4 + s];
    }

    float b1v[K4];
#pragma unroll
    for (int j = 0; j < 5; ++j) *(float4*)&b1v[j * 4] = ((const float4*)b1)[j];

    __syncthreads();

    float zp[4][K4];
#pragma unroll
    for (int t = 0; t < 4; ++t)
#pragma unroll
        for (int k = 0; k < K4; ++k) zp[t][k] = 0.f;

#pragma unroll
    for (int i = 0; i < 4; ++i) {
#pragma unroll
        for (int cc = 0; cc < 4; ++cc) {
            const int f = i * 16 + s * 4 + cc;
            const float* wr = &sW[f * 32];
            float4 wq[5];
            wq[0] = *(const float4*)(wr + ((0 ^ s) << 2));
            wq[1] = *(const float4*)(wr + ((1 ^ s) << 2));
            wq[2] = *(const float4*)(wr + ((2 ^ s) << 2));
            wq[3] = *(const float4*)(wr + ((3 ^ s) << 2));
            wq[4] = *(const float4*)(wr + 16 + (s << 2));
#pragma unroll
            for (int t = 0; t < 4; ++t) {
                const float4 xt = xv[t][i];
                const float xs = (cc == 0) ? xt.x : (cc == 1) ? xt.y
                               : (cc == 2) ? xt.z : xt.w;
#pragma unroll
                for (int k4 = 0; k4 < 5; ++k4) {
                    zp[t][k4 * 4 + 0] = fmaf(xs, wq[k4].x, zp[t][k4 * 4 + 0]);
                    zp[t][k4 * 4 + 1] = fmaf(xs, wq[k4].y, zp[t][k4 * 4 + 1]);
                    zp[t][k4 * 4 + 2] = fmaf(xs, wq[k4].z, zp[t][k4 * 4 + 2]);
                    zp[t][k4 * 4 + 3] = fmaf(xs, wq[k4].w, zp[t][k4 * 4 + 3]);
                }
            }
        }
    }

    // quad reduce (DPP butterfly, VALU) + predicated store (static reg idx!)
#pragma unroll
    for (int t = 0; t < 4; ++t) {
#pragma unroll
        for (int k = 0; k < K4; ++k) {
            float v = zp[t][k];
            v += qp<0xB1>(v);
            v += qp<0x4E>(v);
            zp[t][k] = v;                  // full quad sum on all 4 lanes
        }
#pragma unroll
        for (int k = 0; k < K4; ++k) {
            if (s == k / 5) {              // one s-group per k; 16 b = 64B chunk
                z[((size_t)(t0 + t) * K4 + k) * BB + b] = zp[t][k] + b1v[k];
            }
        }
    }
}

// ===========================================================================
// K2: recurrence, QUAD PER BATCH (lane s owns gate s: k = 5s..5s+4).
// 1024 waves -> 1 per SIMD on ALL 1024 SIMDs (4x round-2's issue capacity).
// Per-lane weights = 135 floats -> ALL IN REGISTERS, zero LDS in the loop
// (round-2 killer: 125 ds_read_b128/t at VGPR cap).  Gate exchange = 3 DPP
// quad-perms + 1 DPP broadcast per unit (VALU, ~2cyc).  Non-canonical lanes
// carry garbage c (never read); h broadcast from quad-lane 0 (canonical:
// a=i, xor1=f, xor2=g, xor2(xor1)=o).  Branchless nonlinearity:
// sig = rcp(e^-x + 1);  tanh = 1 - 2*rcp(e^2x + 1)  via lane-const m/A/B.
// z[t][k][b] reads: 4x64B chunks per instr, prefetched 1 t ahead (L3-hit).
// ~390 VALU/t ~ 800 cyc -> target 50-80 us.
// ===========================================================================
__global__ __launch_bounds__(64) __attribute__((amdgpu_waves_per_eu(1, 1)))
void rec_kernel(
    const float* __restrict__ z,
    const float* __restrict__ U1,
    const float* __restrict__ W2, const float* __restrict__ U2, const float* __restrict__ b2,
    const float* __restrict__ W3, const float* __restrict__ U3, const float* __restrict__ b3,
    const float* __restrict__ Wd, const float* __restrict__ bd,
    float* __restrict__ out)
{
    const int lane = threadIdx.x;
    const int q    = lane >> 2;
    const int s    = lane & 3;
    const size_t b = (size_t)blockIdx.x * 16 + q;
    const int k0   = s * 5;

    // per-lane weight slice: gate s's 5 columns of each matrix (135 regs)
    float U1c[HH][HH], W2c[HH][HH], U2c[HH][HH], W3c[HH][HH], U3c[HH][HH];
#pragma unroll
    for (int d = 0; d < HH; ++d) {
#pragma unroll
        for (int u = 0; u < HH; ++u) {
            const int idx = d * K4 + k0 + u;
            U1c[d][u] = U1[idx];
            W2c[d][u] = W2[idx];
            U2c[d][u] = U2[idx];
            W3c[d][u] = W3[idx];
            U3c[d][u] = U3[idx];
        }
    }
    float b2c[HH], b3c[HH];
#pragma unroll
    for (int u = 0; u < HH; ++u) { b2c[u] = b2[k0 + u]; b3c[u] = b3[k0 + u]; }

    const float mco = (s == 2) ? 2.0f : -1.0f;   // lane2 = g-gate = tanh
    const float aco = (s == 2) ? -2.0f : 1.0f;
    const float bco = (s == 2) ? 1.0f : 0.0f;

    auto gate = [&](float v) -> float {
        const float y = __builtin_amdgcn_rcpf(__expf(mco * v) + 1.0f);
        return fmaf(aco, y, bco);
    };
    auto combine = [&](float (&a)[HH], float (&cs)[HH], float (&hs)[HH]) {
#pragma unroll
        for (int u = 0; u < HH; ++u) {
            const float av = a[u];              // lane0: i
            const float fv = qp<0xB1>(av);      // lane0: f
            const float gv = qp<0x4E>(av);      // lane0: g
            const float ov = qp<0x4E>(fv);      // lane0: o (lane2's fv = lane3's a)
            cs[u] = fmaf(fv, cs[u], av * gv);   // canonical on lane0 only
            hs[u] = qp<0x00>(ov * tanhf_fast(cs[u]));  // broadcast lane0's h
        }
    };

    float h1[HH] = {}, h2[HH] = {}, h3[HH] = {};
    float c1[HH] = {}, c2[HH] = {}, c3[HH] = {};

    float zg[HH], zn[HH];
#pragma unroll
    for (int u = 0; u < HH; ++u) zg[u] = z[(size_t)(k0 + u) * BB + b];

#pragma unroll 1
    for (int t = 0; t < TT_; ++t) {
        if (t < TT_ - 1) {                      // prefetch next t (L3-resident)
#pragma unroll
            for (int u = 0; u < HH; ++u)
                zn[u] = z[((size_t)(t + 1) * K4 + k0 + u) * BB + b];
        }
        float a[HH];
        // ---- layer 1 (z has xW1+b1)
#pragma unroll
        for (int u = 0; u < HH; ++u) {
            float v = zg[u];
#pragma unroll
            for (int d = 0; d < HH; ++d) v = fmaf(h1[d], U1c[d][u], v);
            a[u] = gate(v);
        }
        combine(a, c1, h1);
        // ---- layer 2
#pragma unroll
        for (int u = 0; u < HH; ++u) {
            float v = b2c[u];
#pragma unroll
            for (int d = 0; d < HH; ++d) v = fmaf(h1[d], W2c[d][u], v);
#pragma unroll
            for (int d = 0; d < HH; ++d) v = fmaf(h2[d], U2c[d][u], v);
            a[u] = gate(v);
        }
        combine(a, c2, h2);
        // ---- layer 3
#pragma unroll
        for (int u = 0; u < HH; ++u) {
            float v = b3c[u];
#pragma unroll
            for (int d = 0; d < HH; ++d) v = fmaf(h2[d], W3c[d][u], v);
#pragma unroll
            for (int d = 0; d < HH; ++d) v = fmaf(h3[d], U3c[d][u], v);
            a[u] = gate(v);
        }
        combine(a, c3, h3);

        if (t < TT_ - 1) {
#pragma unroll
            for (int u = 0; u < HH; ++u) zg[u] = zn[u];
        }
    }

    // ---- output head (h3 broadcast-consistent on all lanes)
    if (s < NOUT) {
        float acc = bd[s];
#pragma unroll
        for (int d = 0; d < HH; ++d) acc = fmaf(h3[d], Wd[d * NOUT + s], acc);
        out[b * NOUT + s] = acc;
    }
}

extern "C" void kernel_launch(void* const* d_in, const int* in_sizes, int n_in,
                              void* d_out, int out_size, void* d_ws, size_t ws_size,
                              hipStream_t stream) {
    const float* x   = (const float*)d_in[0];
    const float* W1  = (const float*)d_in[1];
    const float* U1  = (const float*)d_in[2];
    const float* b1  = (const float*)d_in[3];
    const float* W2  = (const float*)d_in[4];
    const float* U2  = (const float*)d_in[5];
    const float* b2  = (const float*)d_in[6];
    const float* W3  = (const float*)d_in[7];
    const float* U3  = (const float*)d_in[8];
    const float* b3  = (const float*)d_in[9];
    const float* Wd  = (const float*)d_in[10];
    const float* bdp = (const float*)d_in[11];
    float* out = (float*)d_out;

    // workspace: z in [T][20][B] fp32 = 131.1 MB
    float* zws = (float*)d_ws;

    dim3 pgrid(BB / 64, TT_ / 4);
    proj_kernel<<<pgrid, 256, 0, stream>>>(x, W1, b1, zws);
    rec_kernel<<<BB / 16, 64, 0, stream>>>(zws, U1, W2, U2, b2, W3, U3, b3, Wd, bdp, out);
}